// Round 1
// baseline (5749.967 us; speedup 1.0000x reference)
//
#include <hip/hip_runtime.h>
#include <math.h>

#define CDIV(a,b) (((a)+(b)-1)/(b))

static constexpr int NE  = 512;   // n_embed
static constexpr int EH  = 8;     // encoder heads
static constexpr int EHD = 64;    // encoder head dim
static constexpr int DHN = 16;    // decoder heads
static constexpr int HDD = 32;    // decoder head dim
static constexpr int NM  = 80;    // mels
static constexpr int TMl = 1500;  // mel time
static constexpr int TP  = 1502;  // padded time
static constexpr int TA  = 750;   // audio ctx
static constexpr int LQ  = 448;   // text ctx
static constexpr int NB  = 4;     // batch
static constexpr int OV  = 51904; // padded vocab

// ---------------- elementwise / layout kernels ----------------

__global__ void k_transpose_mels(const float* __restrict__ mels, float* __restrict__ melsT) {
    long idx = (long)blockIdx.x * blockDim.x + threadIdx.x;
    long total = (long)NB * TP * NM;
    if (idx >= total) return;
    int ci = (int)(idx % NM);
    int t  = (int)((idx / NM) % TP);
    int b  = (int)(idx / ((long)NM * TP));
    float v = 0.f;
    if (t >= 1 && t <= TMl) v = mels[((long)b * NM + ci) * TMl + (t - 1)];
    melsT[idx] = v;
}

__global__ void k_zero_x1t_pads(float* __restrict__ x1t) {
    int idx = blockIdx.x * blockDim.x + threadIdx.x;
    if (idx >= NB * 2 * NE) return;
    int c = idx % NE;
    int r = (idx / NE) % 2;
    int b = idx / (NE * 2);
    int t = r ? (TP - 1) : 0;
    x1t[((long)b * TP + t) * NE + c] = 0.f;
}

__global__ void k_repack_w(const float* __restrict__ w, float* __restrict__ wr, int O, int I) {
    // w[o][i][k] -> wr[k][o][i]
    long idx = (long)blockIdx.x * blockDim.x + threadIdx.x;
    long total = (long)O * I * 3;
    if (idx >= total) return;
    int k = (int)(idx % 3);
    int i = (int)((idx / 3) % I);
    int o = (int)(idx / ((long)3 * I));
    wr[((long)k * O + o) * I + i] = w[idx];
}

__global__ void k_add_encpos(float* __restrict__ x) {
    long idx = (long)blockIdx.x * blockDim.x + threadIdx.x;
    long total = (long)NB * TA * NE;
    if (idx >= total) return;
    int c = (int)(idx % NE);
    int t = (int)((idx / NE) % TA);
    double inc = log(10000.0) / 255.0;
    int j = c & 255;
    double st = (double)t * exp(-inc * (double)j);
    float p = (c < 256) ? (float)sin(st) : (float)cos(st);
    x[idx] += p;
}

__global__ void k_embed(const int* __restrict__ ids, const float* __restrict__ ew,
                        const float* __restrict__ pos, float* __restrict__ ctx) {
    long idx = (long)blockIdx.x * blockDim.x + threadIdx.x;
    long total = (long)NB * LQ * NE;
    if (idx >= total) return;
    int c = (int)(idx % NE);
    int t = (int)((idx / NE) % LQ);
    int b = (int)(idx / ((long)NE * LQ));
    int id = ids[b * LQ + t];
    float v = ew[(long)id * NE + c] * 22.62741699796952f;
    if (t >= 1) v += pos[(long)(t - 1) * NE + c];
    ctx[idx] = v;
}

__global__ void k_bcast_pos(const float* __restrict__ pos, float* __restrict__ dst, int Bn) {
    long idx = (long)blockIdx.x * blockDim.x + threadIdx.x;
    long total = (long)Bn * LQ * NE;
    if (idx >= total) return;
    int c = (int)(idx % NE);
    int t = (int)((idx / NE) % LQ);
    dst[idx] = pos[(long)t * NE + c];
}

__global__ void k_ropetab(float* __restrict__ ctab, float* __restrict__ stab) {
    int idx = blockIdx.x * blockDim.x + threadIdx.x;
    if (idx >= LQ * 16) return;
    int m = idx % 16;
    int t = idx / 16;
    double inv = pow(10000.0, -(double)(2 * m) / 32.0);
    double f = (double)t * inv;
    ctab[idx] = (float)cos(f);
    stab[idx] = (float)sin(f);
}

__global__ void k_rope(float* __restrict__ x, int Bn, int shiftK,
                       const float* __restrict__ ctab, const float* __restrict__ stab) {
    long idx = (long)blockIdx.x * blockDim.x + threadIdx.x;
    long total = (long)Bn * LQ * DHN * 16;
    if (idx >= total) return;
    int m = (int)(idx % 16);
    int h = (int)((idx / 16) % DHN);
    int t = (int)((idx / (16 * DHN)) % LQ);
    int b = (int)(idx / ((long)16 * DHN * LQ));
    int tt = shiftK ? (t > 0 ? t - 1 : 0) : t;
    float c = ctab[tt * 16 + m];
    float s = stab[tt * 16 + m];
    long base = (((long)b * LQ + t) * DHN + h) * HDD;
    float x1 = x[base + m];
    float x2 = x[base + 16 + m];
    x[base + m]      = x1 * c + x2 * s;
    x[base + 16 + m] = -x1 * s + x2 * c;
}

// ---------------- rms / decorrelate / softmax ----------------

__global__ void k_rms512(const float* __restrict__ src, float* __restrict__ dst, int rows) {
    int wave = blockIdx.x * (blockDim.x >> 6) + (threadIdx.x >> 6);
    int lane = threadIdx.x & 63;
    if (wave >= rows) return;
    const float* s = src + (long)wave * NE;
    float4 a = *(const float4*)(s + lane * 4);
    float4 b = *(const float4*)(s + 256 + lane * 4);
    float ss = a.x*a.x + a.y*a.y + a.z*a.z + a.w*a.w
             + b.x*b.x + b.y*b.y + b.z*b.z + b.w*b.w;
    for (int m = 32; m >= 1; m >>= 1) ss += __shfl_xor(ss, m, 64);
    float sc = rsqrtf(ss / 512.f + 1e-6f);
    float* d = dst + (long)wave * NE;
    a.x *= sc; a.y *= sc; a.z *= sc; a.w *= sc;
    b.x *= sc; b.y *= sc; b.z *= sc; b.w *= sc;
    *(float4*)(d + lane * 4) = a;
    *(float4*)(d + 256 + lane * 4) = b;
}

template<int D>
__global__ void k_rms_heads(float* __restrict__ x, long rows) {
    const int RPW = 64 / D;
    long wave = (long)blockIdx.x * (blockDim.x >> 6) + (threadIdx.x >> 6);
    int lane = threadIdx.x & 63;
    long row = wave * RPW + lane / D;
    if (row >= rows) return;
    int col = lane % D;
    long idx = row * D + col;
    float v = x[idx];
    float ss = v * v;
    for (int m = D / 2; m >= 1; m >>= 1) ss += __shfl_xor(ss, m, 64);
    x[idx] = v * rsqrtf(ss / (float)D + 1e-6f);
}

template<int D>
__global__ void k_decorrelate(float* __restrict__ o, const float* __restrict__ v, long rows) {
    const int RPW = 64 / D;
    long wave = (long)blockIdx.x * (blockDim.x >> 6) + (threadIdx.x >> 6);
    int lane = threadIdx.x & 63;
    long row = wave * RPW + lane / D;
    if (row >= rows) return;
    int col = lane % D;
    long idx = row * D + col;
    float ov = o[idx];
    float vv = v[idx];
    float dov = ov * vv;
    float dvv = vv * vv;
    for (int m = D / 2; m >= 1; m >>= 1) {
        dov += __shfl_xor(dov, m, 64);
        dvv += __shfl_xor(dvv, m, 64);
    }
    float nv = sqrtf(dvv);
    float c = fmaxf(nv, 1e-9f);
    o[idx] = ov - (dov / (c * c)) * vv;
}

__global__ void k_softmax(float* __restrict__ s, int H, int Lq, int Lk,
                          int causal, const int* __restrict__ ids, long nrows) {
    long row = (long)blockIdx.x * (blockDim.x >> 6) + (threadIdx.x >> 6);
    if (row >= nrows) return;
    int lane = threadIdx.x & 63;
    int qt = (int)(row % Lq);
    long z = row / Lq;
    int b = (int)(z / H);
    float* p = s + row * (long)Lk;
    int cnt = (Lk + 63) >> 6;
    float vals[12];
    float mx = -INFINITY;
    for (int i = 0; i < cnt; i++) {
        int k = lane + (i << 6);
        float v = -INFINITY;
        if (k < Lk) {
            v = p[k];
            if (causal && k > qt) v = -INFINITY;
            if (ids && ids[(long)b * Lk + k] == 0) v = -INFINITY;
        }
        vals[i] = v;
        mx = fmaxf(mx, v);
    }
    for (int m = 32; m >= 1; m >>= 1) mx = fmaxf(mx, __shfl_xor(mx, m, 64));
    float sum = 0.f;
    for (int i = 0; i < cnt; i++) {
        float e = expf(vals[i] - mx);
        vals[i] = e;
        sum += e;
    }
    for (int m = 32; m >= 1; m >>= 1) sum += __shfl_xor(sum, m, 64);
    float inv = 1.f / sum;
    for (int i = 0; i < cnt; i++) {
        int k = lane + (i << 6);
        if (k < Lk) p[k] = vals[i] * inv;
    }
}

// ---------------- generic batched GEMM ----------------
// C[z] = act( alpha * A[z] (.) B[z](^T) + bias + beta*C[z] )
// NT: A (M,K) lda, B (N,K) ldb.  NN: A (M,K) lda, B (K,N) ldb.
// z -> b = z/H, h = z%H; ptr += b*s?b + h*s?h.

template<bool TRANSB>
__global__ __launch_bounds__(256) void k_gemm(
    const float* __restrict__ A, const float* __restrict__ Bm,
    const float* __restrict__ bias, float* __restrict__ C,
    int M, int N, int K, int lda, int ldb, int ldc,
    long sAb, long sAh, long sBb, long sBh, long sCb, long sCh, int H,
    float alpha, float beta, int act)
{
    __shared__ __align__(16) float As[16][68];
    __shared__ __align__(16) float Bs[16][68];
    int z = blockIdx.z;
    int bb = z / H, hh = z % H;
    A  += (long)bb * sAb + (long)hh * sAh;
    Bm += (long)bb * sBb + (long)hh * sBh;
    C  += (long)bb * sCb + (long)hh * sCh;
    int m0 = blockIdx.y * 64, n0 = blockIdx.x * 64;
    int tid = threadIdx.x;
    int tm0 = (tid / 16) * 4, tn0 = (tid % 16) * 4;
    float acc[4][4] = {};
    for (int k0 = 0; k0 < K; k0 += 16) {
        {
            int k = tid & 15, mr = tid >> 4;
            #pragma unroll
            for (int i = 0; i < 4; i++) {
                int m = mr + i * 16;
                float v = 0.f;
                if (m0 + m < M && k0 + k < K) v = A[(long)(m0 + m) * lda + k0 + k];
                As[k][m] = v;
            }
            if (TRANSB) {
                #pragma unroll
                for (int i = 0; i < 4; i++) {
                    int n = mr + i * 16;
                    float v = 0.f;
                    if (n0 + n < N && k0 + k < K) v = Bm[(long)(n0 + n) * ldb + k0 + k];
                    Bs[k][n] = v;
                }
            } else {
                int n = tid & 63, kr = tid >> 6;
                #pragma unroll
                for (int i = 0; i < 4; i++) {
                    int k2 = kr + i * 4;
                    float v = 0.f;
                    if (k0 + k2 < K && n0 + n < N) v = Bm[(long)(k0 + k2) * ldb + n0 + n];
                    Bs[k2][n] = v;
                }
            }
        }
        __syncthreads();
        #pragma unroll
        for (int kk = 0; kk < 16; kk++) {
            float4 av = *(const float4*)&As[kk][tm0];
            float4 bv = *(const float4*)&Bs[kk][tn0];
            float aa[4] = {av.x, av.y, av.z, av.w};
            float bbv[4] = {bv.x, bv.y, bv.z, bv.w};
            #pragma unroll
            for (int i = 0; i < 4; i++)
                #pragma unroll
                for (int j = 0; j < 4; j++)
                    acc[i][j] += aa[i] * bbv[j];
        }
        __syncthreads();
    }
    #pragma unroll
    for (int i = 0; i < 4; i++) {
        int m = m0 + tm0 + i;
        if (m >= M) continue;
        #pragma unroll
        for (int j = 0; j < 4; j++) {
            int n = n0 + tn0 + j;
            if (n >= N) continue;
            float v = alpha * acc[i][j];
            if (bias) v += bias[n];
            long off = (long)m * ldc + n;
            if (beta != 0.f) v += beta * C[off];
            if (act) v = 0.5f * v * (1.f + erff(v * 0.70710678118654752f));
            C[off] = v;
        }
    }
}

static inline void gemm(hipStream_t st, bool tb, const float* A, const float* Bm,
                        const float* bias, float* C, int M, int N, int K,
                        int lda, int ldb, int ldc,
                        long sAb, long sAh, long sBb, long sBh, long sCb, long sCh,
                        int Z, int H, float alpha, float beta, int act)
{
    dim3 g(CDIV(N, 64), CDIV(M, 64), Z), blk(256);
    if (tb) k_gemm<true ><<<g, blk, 0, st>>>(A, Bm, bias, C, M, N, K, lda, ldb, ldc,
                                             sAb, sAh, sBb, sBh, sCb, sCh, H, alpha, beta, act);
    else    k_gemm<false><<<g, blk, 0, st>>>(A, Bm, bias, C, M, N, K, lda, ldb, ldc,
                                             sAb, sAh, sBb, sBh, sCb, sCh, H, alpha, beta, act);
}

// ---------------- launcher ----------------

extern "C" void kernel_launch(void* const* d_in, const int* in_sizes, int n_in,
                              void* d_out, int out_size, void* d_ws, size_t ws_size,
                              hipStream_t stream)
{
    const float* mels = (const float*)d_in[0];
    const int*   ids  = (const int*)  d_in[1];
    const float* c1w  = (const float*)d_in[2];
    const float* c1b  = (const float*)d_in[3];
    const float* c2w  = (const float*)d_in[4];
    const float* c2b  = (const float*)d_in[5];
    const float* eqw  = (const float*)d_in[6];
    const float* eqb  = (const float*)d_in[7];
    const float* ekw  = (const float*)d_in[8];
    const float* ekb  = (const float*)d_in[9];
    const float* evw  = (const float*)d_in[10];
    const float* evb  = (const float*)d_in[11];
    const float* eow  = (const float*)d_in[12];
    const float* eob  = (const float*)d_in[13];
    const float* efcw = (const float*)d_in[14];
    const float* efcb = (const float*)d_in[15];
    const float* epjw = (const float*)d_in[16];
    const float* epjb = (const float*)d_in[17];
    const float* sqw  = (const float*)d_in[18];
    const float* sqb  = (const float*)d_in[19];
    const float* skw  = (const float*)d_in[20];
    const float* skb  = (const float*)d_in[21];
    const float* svw  = (const float*)d_in[22];
    const float* svb  = (const float*)d_in[23];
    const float* soww = (const float*)d_in[24];
    const float* sob  = (const float*)d_in[25];
    const float* cqw  = (const float*)d_in[26];
    const float* cqb  = (const float*)d_in[27];
    const float* ckw  = (const float*)d_in[28];
    const float* ckb  = (const float*)d_in[29];
    const float* cvw  = (const float*)d_in[30];
    const float* cvb  = (const float*)d_in[31];
    const float* coww = (const float*)d_in[32];
    const float* cob  = (const float*)d_in[33];
    const float* fcw  = (const float*)d_in[34];
    const float* fcb  = (const float*)d_in[35];
    const float* pjw  = (const float*)d_in[36];
    const float* pjb  = (const float*)d_in[37];
    const float* embw = (const float*)d_in[38];
    const float* pose = (const float*)d_in[39];
    float* out = (float*)d_out;

    float* ws = (float*)d_ws;
    long off = 0;
    auto alloc = [&](long n) { float* p = ws + off; off += n; return p; };
    float* melsT = alloc((long)NB * TP * NM);
    float* x1t   = alloc((long)NB * TP * NE);
    float* w1r   = alloc(3L * NE * NM);
    float* w2r   = alloc(3L * NE * NE);
    float* xenc  = alloc((long)NB * TA * NE);
    float* hbuf  = alloc((long)NB * TA * NE);
    float* qbuf  = alloc((long)NB * TA * NE);
    float* kbuf  = alloc((long)NB * TA * NE);
    float* vbuf  = alloc((long)NB * TA * NE);
    float* obuf  = alloc((long)NB * TA * NE);
    float* fcbuf = alloc((long)NB * TA * 2048);
    float* sc    = alloc((long)NB * DHN * LQ * TA); // 21.5M floats; covers all 3 attns
    float* audk  = alloc((long)NB * TA * NE);
    float* audv  = alloc((long)NB * TA * NE);
    float* ctx   = alloc((long)NB * LQ * NE);
    float* q0r   = alloc((long)LQ * NE);
    float* qh    = alloc((long)NB * LQ * NE);
    float* kh    = alloc((long)NB * LQ * NE);
    float* vh    = alloc((long)NB * LQ * NE);
    float* res   = alloc((long)NB * LQ * NE);
    float* t1    = alloc((long)NB * LQ * NE);
    float* odec  = alloc((long)NB * LQ * NE);
    float* ctab  = alloc((long)LQ * 16);
    float* stab  = alloc((long)LQ * 16);
    (void)ws_size; (void)in_sizes; (void)n_in; (void)out_size;

    const int MA = NB * TA;  // 3000 encoder rows
    const int MD = NB * LQ;  // 1792 decoder rows
    const float dscale = 0.17677669529663687f; // 1/sqrt(32)

    // ---- conv front-end (as 3-tap batched GEMMs) ----
    k_transpose_mels<<<CDIV((long)NB * TP * NM, 256), 256, 0, stream>>>(mels, melsT);
    k_repack_w<<<CDIV(3L * NE * NM, 256), 256, 0, stream>>>(c1w, w1r, NE, NM);
    k_repack_w<<<CDIV(3L * NE * NE, 256), 256, 0, stream>>>(c2w, w2r, NE, NE);
    k_zero_x1t_pads<<<CDIV(NB * 2 * NE, 256), 256, 0, stream>>>(x1t);
    for (int kk = 0; kk < 3; kk++) {
        bool last = (kk == 2);
        gemm(stream, true, melsT + kk * NM, w1r + (long)kk * NE * NM,
             last ? c1b : nullptr, x1t + NE,
             TMl, NE, NM, NM, NM, NE,
             (long)TP * NM, 0, 0, 0, (long)TP * NE, 0,
             NB, 1, 1.f, kk ? 1.f : 0.f, last ? 1 : 0);
    }
    for (int kk = 0; kk < 3; kk++) {
        bool last = (kk == 2);
        gemm(stream, true, x1t + kk * NE, w2r + (long)kk * NE * NE,
             last ? c2b : nullptr, xenc,
             TA, NE, NE, 2 * NE, NE, NE,
             (long)TP * NE, 0, 0, 0, (long)TA * NE, 0,
             NB, 1, 1.f, kk ? 1.f : 0.f, last ? 1 : 0);
    }
    k_add_encpos<<<CDIV((long)NB * TA * NE, 256), 256, 0, stream>>>(xenc);

    // ---- encoder layers ----
    for (int l = 0; l < 2; l++) {
        const float* qw = eqw + (long)l * NE * NE; const float* qb = eqb + l * NE;
        const float* kw = ekw + (long)l * NE * NE; const float* kb = ekb + l * NE;
        const float* vw = evw + (long)l * NE * NE; const float* vb = evb + l * NE;
        const float* ow = eow + (long)l * NE * NE; const float* ob = eob + l * NE;
        const float* fw = efcw + (long)l * 2048 * NE; const float* fb = efcb + l * 2048;
        const float* pw = epjw + (long)l * NE * 2048; const float* pb = epjb + l * NE;

        k_rms512<<<CDIV(MA, 4), 256, 0, stream>>>(xenc, hbuf, MA);
        gemm(stream, true, hbuf, qw, qb, qbuf, MA, NE, NE, NE, NE, NE, 0,0,0,0,0,0, 1,1, 1.f, 0.f, 0);
        gemm(stream, true, hbuf, kw, kb, kbuf, MA, NE, NE, NE, NE, NE, 0,0,0,0,0,0, 1,1, 1.f, 0.f, 0);
        gemm(stream, true, hbuf, vw, vb, vbuf, MA, NE, NE, NE, NE, NE, 0,0,0,0,0,0, 1,1, 1.f, 0.f, 0);
        k_rms_heads<64><<<CDIV((long)MA * EH, 4), 256, 0, stream>>>(qbuf, (long)MA * EH);
        k_rms_heads<64><<<CDIV((long)MA * EH, 4), 256, 0, stream>>>(kbuf, (long)MA * EH);
        gemm(stream, true, qbuf, kbuf, nullptr, sc, TA, TA, EHD, NE, NE, TA,
             (long)TA * NE, EHD, (long)TA * NE, EHD, (long)EH * TA * TA, (long)TA * TA,
             NB * EH, EH, 0.125f, 0.f, 0);
        k_softmax<<<CDIV((long)NB * EH * TA, 4), 256, 0, stream>>>(sc, EH, TA, TA, 0, nullptr, (long)NB * EH * TA);
        gemm(stream, false, sc, vbuf, nullptr, obuf, TA, EHD, TA, TA, NE, NE,
             (long)EH * TA * TA, (long)TA * TA, (long)TA * NE, EHD, (long)TA * NE, EHD,
             NB * EH, EH, 1.f, 0.f, 0);
        k_decorrelate<64><<<CDIV((long)MA * EH, 4), 256, 0, stream>>>(obuf, vbuf, (long)MA * EH);
        gemm(stream, true, obuf, ow, ob, xenc, MA, NE, NE, NE, NE, NE, 0,0,0,0,0,0, 1,1, 1.f, 1.f, 0);

        k_rms512<<<CDIV(MA, 4), 256, 0, stream>>>(xenc, hbuf, MA);
        gemm(stream, true, hbuf, fw, fb, fcbuf, MA, 2048, NE, NE, NE, 2048, 0,0,0,0,0,0, 1,1, 1.f, 0.f, 1);
        gemm(stream, true, fcbuf, pw, pb, xenc, MA, NE, 2048, 2048, 2048, NE, 0,0,0,0,0,0, 1,1, 1.f, 1.f, 0);
    }

    // ---- cross K/V from encoder output ----
    k_rms512<<<CDIV(MA, 4), 256, 0, stream>>>(xenc, hbuf, MA);
    gemm(stream, true, hbuf, ckw, ckb, audk, MA, NE, NE, NE, NE, NE, 0,0,0,0,0,0, 1,1, 1.f, 0.f, 0);
    k_rms_heads<32><<<CDIV((long)MA * DHN, 8), 256, 0, stream>>>(audk, (long)MA * DHN);
    gemm(stream, true, hbuf, cvw, cvb, audv, MA, NE, NE, NE, NE, NE, 0,0,0,0,0,0, 1,1, 1.f, 0.f, 0);

    // ---- decoder ----
    k_embed<<<CDIV((long)NB * LQ * NE, 256), 256, 0, stream>>>(ids, embw, pose, ctx);
    k_rms512<<<CDIV(MD, 4), 256, 0, stream>>>(ctx, ctx, MD);
    k_ropetab<<<CDIV(LQ * 16, 256), 256, 0, stream>>>(ctab, stab);

    k_bcast_pos<<<CDIV((long)LQ * NE, 256), 256, 0, stream>>>(pose, q0r, 1);
    k_rms512<<<CDIV(LQ, 4), 256, 0, stream>>>(q0r, q0r, LQ);
    gemm(stream, true, q0r, sqw, sqb, qh, LQ, NE, NE, NE, NE, NE, 0,0,0,0,0,0, 1,1, 1.f, 0.f, 0);
    k_rope<<<CDIV((long)LQ * DHN * 16, 256), 256, 0, stream>>>(qh, 1, 0, ctab, stab);
    k_rms_heads<32><<<CDIV((long)LQ * DHN, 8), 256, 0, stream>>>(qh, (long)LQ * DHN);

    gemm(stream, true, ctx, skw, skb, kh, MD, NE, NE, NE, NE, NE, 0,0,0,0,0,0, 1,1, 1.f, 0.f, 0);
    k_rope<<<CDIV((long)NB * LQ * DHN * 16, 256), 256, 0, stream>>>(kh, NB, 1, ctab, stab);
    k_rms_heads<32><<<CDIV((long)MD * DHN, 8), 256, 0, stream>>>(kh, (long)MD * DHN);
    gemm(stream, true, ctx, svw, svb, vh, MD, NE, NE, NE, NE, NE, 0,0,0,0,0,0, 1,1, 1.f, 0.f, 0);

    // self-attention (qh shared across batch: sAb = 0)
    gemm(stream, true, qh, kh, nullptr, sc, LQ, LQ, HDD, NE, NE, LQ,
         0, HDD, (long)LQ * NE, HDD, (long)DHN * LQ * LQ, (long)LQ * LQ,
         NB * DHN, DHN, dscale, 0.f, 0);
    k_softmax<<<CDIV((long)NB * DHN * LQ, 4), 256, 0, stream>>>(sc, DHN, LQ, LQ, 1, ids, (long)NB * DHN * LQ);
    gemm(stream, false, sc, vh, nullptr, odec, LQ, HDD, LQ, LQ, NE, NE,
         (long)DHN * LQ * LQ, (long)LQ * LQ, (long)LQ * NE, HDD, (long)LQ * NE, HDD,
         NB * DHN, DHN, 1.f, 0.f, 0);
    k_decorrelate<32><<<CDIV((long)MD * DHN, 8), 256, 0, stream>>>(odec, vh, (long)MD * DHN);
    k_bcast_pos<<<CDIV((long)NB * LQ * NE, 256), 256, 0, stream>>>(pose, res, NB);
    gemm(stream, true, odec, soww, sob, res, MD, NE, NE, NE, NE, NE, 0,0,0,0,0,0, 1,1, 1.f, 1.f, 0);

    // cross-attention
    k_rms512<<<CDIV(MD, 4), 256, 0, stream>>>(res, t1, MD);
    gemm(stream, true, t1, cqw, cqb, qh, MD, NE, NE, NE, NE, NE, 0,0,0,0,0,0, 1,1, 1.f, 0.f, 0);
    k_rope<<<CDIV((long)NB * LQ * DHN * 16, 256), 256, 0, stream>>>(qh, NB, 0, ctab, stab);
    k_rms_heads<32><<<CDIV((long)MD * DHN, 8), 256, 0, stream>>>(qh, (long)MD * DHN);
    gemm(stream, true, qh, audk, nullptr, sc, LQ, TA, HDD, NE, NE, TA,
         (long)LQ * NE, HDD, (long)TA * NE, HDD, (long)DHN * LQ * TA, (long)LQ * TA,
         NB * DHN, DHN, dscale, 0.f, 0);
    k_softmax<<<CDIV((long)NB * DHN * LQ, 4), 256, 0, stream>>>(sc, DHN, LQ, TA, 0, nullptr, (long)NB * DHN * LQ);
    gemm(stream, false, sc, audv, nullptr, odec, LQ, HDD, TA, TA, NE, NE,
         (long)DHN * LQ * TA, (long)LQ * TA, (long)TA * NE, HDD, (long)LQ * NE, HDD,
         NB * DHN, DHN, 1.f, 0.f, 0);
    gemm(stream, true, odec, coww, cob, res, MD, NE, NE, NE, NE, NE, 0,0,0,0,0,0, 1,1, 1.f, 1.f, 0);

    // decoder MLP
    k_rms512<<<CDIV(MD, 4), 256, 0, stream>>>(res, t1, MD);
    gemm(stream, true, t1, fcw, fcb, fcbuf, MD, 2048, NE, NE, NE, 2048, 0,0,0,0,0,0, 1,1, 1.f, 0.f, 1);
    gemm(stream, true, fcbuf, pjw, pjb, res, MD, NE, 2048, 2048, 2048, NE, 0,0,0,0,0,0, 1,1, 1.f, 1.f, 0);

    // logits
    k_rms512<<<CDIV(MD, 4), 256, 0, stream>>>(res, t1, MD);
    gemm(stream, true, t1, embw, nullptr, out, MD, OV, NE, NE, NE, OV,
         0,0,0,0,0,0, 1,1, 1.f, 0.f, 0);
}